// Round 6
// baseline (514.260 us; speedup 1.0000x reference)
//
#include <hip/hip_runtime.h>
#include <hip/hip_bf16.h>

#define BH_N 16
#define SEQ 2048
#define DH 128

typedef __attribute__((ext_vector_type(8))) short bf16x8;
typedef __attribute__((ext_vector_type(4))) float f32x4;

__device__ __forceinline__ short f2bf(float x) {
    union { __hip_bfloat16 b; short s; } u;
    u.b = __float2bfloat16(x);
    return u.s;
}

// ---------- prep: K -> bf16 [bh][key][d]; V -> bf16 transposed [bh][d][key] ----------
__global__ __launch_bounds__(256) void prep_kv(
    const float* __restrict__ kp, const float* __restrict__ vp,
    unsigned short* __restrict__ Kb, unsigned short* __restrict__ Vt)
{
    const int tid  = threadIdx.x;
    const int kb64 = blockIdx.x * 64;
    const int bh   = blockIdx.y;
    const float* Ksrc = kp + ((size_t)bh * SEQ + kb64) * DH;
    const float* Vsrc = vp + ((size_t)bh * SEQ + kb64) * DH;
    unsigned short* Kdst = Kb + ((size_t)bh * SEQ + kb64) * DH;
    unsigned short* Vdst = Vt + (size_t)bh * DH * SEQ + kb64;

    #pragma unroll
    for (int i = 0; i < 8; ++i) {
        const int f4 = i * 256 + tid;
        const float4 kv = *(const float4*)(Ksrc + (size_t)f4 * 4);
        ushort4 o;
        o.x = (unsigned short)f2bf(kv.x); o.y = (unsigned short)f2bf(kv.y);
        o.z = (unsigned short)f2bf(kv.z); o.w = (unsigned short)f2bf(kv.w);
        *(ushort4*)(Kdst + (size_t)f4 * 4) = o;
    }
    const int key   = tid & 63;
    const int dbase = (tid >> 6) * 4;
    #pragma unroll
    for (int j = 0; j < 8; ++j) {
        const int d0 = dbase + j * 16;
        const float4 vv = *(const float4*)(Vsrc + (size_t)key * DH + d0);
        Vdst[(size_t)(d0 + 0) * SEQ + key] = (unsigned short)f2bf(vv.x);
        Vdst[(size_t)(d0 + 1) * SEQ + key] = (unsigned short)f2bf(vv.y);
        Vdst[(size_t)(d0 + 2) * SEQ + key] = (unsigned short)f2bf(vv.z);
        Vdst[(size_t)(d0 + 3) * SEQ + key] = (unsigned short)f2bf(vv.w);
    }
}

// ---------- main: 512 threads, 8 waves. Block = q-tiles {x, 127-x} (uniform cost) ----------
__global__ __launch_bounds__(512, 8) void attn_main(
    const float* __restrict__ qp, const unsigned short* __restrict__ Kb,
    const unsigned short* __restrict__ Vt, float* __restrict__ outO,
    float* __restrict__ outA)
{
    __shared__ float lspart[8][16];
    __shared__ __align__(16) float pf32[8][16][36];   // +4 pad (16B-aligned rows)
    __shared__ __align__(16) short pbf[8][16][32];
    __shared__ float Osh[16][132];

    // XCD swizzle: group 8 consecutive resident blocks per XCD onto the same bh pair
    const int lin = blockIdx.y * 64 + blockIdx.x;          // 0..1023
    const int sw  = (lin & 7) * 128 + (lin >> 3);          // bijective (1024 % 8 == 0)
    const int bh  = sw >> 6;
    const int x   = sw & 63;

    const int tid  = threadIdx.x;
    const int wv   = tid >> 6;        // 0..7
    const int lane = tid & 63;
    const int c16  = lane & 15;
    const int g    = lane >> 4;
    const float invT = 0.08838834764831845f;   // 1/sqrt(128)

    const unsigned short* Kbh = Kb + (size_t)bh * SEQ * DH;
    const unsigned short* Vbh = Vt + (size_t)bh * DH * SEQ;

    for (int half = 0; half < 2; ++half) {
        const int qt = half ? (127 - x) : x;
        const int qw = qt * 16;
        const size_t qbase = (size_t)bh * SEQ + qw;

        __syncthreads();   // guard lspart/Osh reuse across halves

        // ---- Q fragments: A[row=c16][k=32c+8g+j], pre-scaled ----
        bf16x8 qf[4];
        {
            const float* qrow = qp + (qbase + c16) * DH + g * 8;
            #pragma unroll
            for (int c = 0; c < 4; ++c) {
                const float4 a = *(const float4*)(qrow + c * 32);
                const float4 b = *(const float4*)(qrow + c * 32 + 4);
                bf16x8 f;
                f[0] = f2bf(a.x * invT); f[1] = f2bf(a.y * invT);
                f[2] = f2bf(a.z * invT); f[3] = f2bf(a.w * invT);
                f[4] = f2bf(b.x * invT); f[5] = f2bf(b.y * invT);
                f[6] = f2bf(b.z * invT); f[7] = f2bf(b.w * invT);
                qf[c] = f;
            }
        }

        // ---- phase 1: partial row sums, 16-key tiles strided by 8 waves ----
        float lsr[4] = {0.f, 0.f, 0.f, 0.f};
        const int n16 = qt + 1;
        for (int t = wv; t < n16; t += 8) {
            const int kb = t << 4;
            const unsigned short* kr = Kbh + (size_t)(kb + c16) * DH + g * 8;
            f32x4 acc = {0.f, 0.f, 0.f, 0.f};
            #pragma unroll
            for (int c = 0; c < 4; ++c) {
                const bf16x8 kf = *(const bf16x8*)(kr + c * 32);
                acc = __builtin_amdgcn_mfma_f32_16x16x32_bf16(qf[c], kf, acc, 0, 0, 0);
            }
            const int key = kb + c16;
            const int qr  = qw + g * 4;
            if (key <= qr + 0) lsr[0] += __expf(acc[0]);
            if (key <= qr + 1) lsr[1] += __expf(acc[1]);
            if (key <= qr + 2) lsr[2] += __expf(acc[2]);
            if (key <= qr + 3) lsr[3] += __expf(acc[3]);
        }
        #pragma unroll
        for (int r = 0; r < 4; ++r) {
            float s = lsr[r];
            #pragma unroll
            for (int m = 1; m < 16; m <<= 1) s += __shfl_xor(s, m);
            lsr[r] = s;
        }
        if (c16 == 0) {
            #pragma unroll
            for (int r = 0; r < 4; ++r) lspart[wv][g * 4 + r] = lsr[r];
        }
        __syncthreads();
        float li[4];
        #pragma unroll
        for (int r = 0; r < 4; ++r) {
            float s = 0.f;
            #pragma unroll
            for (int w = 0; w < 8; ++w) s += lspart[w][g * 4 + r];
            li[r] = 1.f / s;
        }

        // ---- phase 2: P writeout + O = P@V, 32-key tiles strided by 8 waves ----
        f32x4 oacc[8];
        #pragma unroll
        for (int d = 0; d < 8; ++d) oacc[d] = (f32x4){0.f, 0.f, 0.f, 0.f};

        const int nt = qw / 32 + 1;
        for (int t = wv; t < nt; t += 8) {
            const int kb32 = t << 5;
            #pragma unroll
            for (int h = 0; h < 2; ++h) {
                const int kb = kb32 + (h << 4);
                const unsigned short* kr = Kbh + (size_t)(kb + c16) * DH + g * 8;
                f32x4 acc = {0.f, 0.f, 0.f, 0.f};
                #pragma unroll
                for (int c = 0; c < 4; ++c) {
                    const bf16x8 kf = *(const bf16x8*)(kr + c * 32);
                    acc = __builtin_amdgcn_mfma_f32_16x16x32_bf16(qf[c], kf, acc, 0, 0, 0);
                }
                const int key = kb + c16;
                const int qr  = qw + g * 4;
                const float p0 = (key <= qr + 0) ? __expf(acc[0]) * li[0] : 0.f;
                const float p1 = (key <= qr + 1) ? __expf(acc[1]) * li[1] : 0.f;
                const float p2 = (key <= qr + 2) ? __expf(acc[2]) * li[2] : 0.f;
                const float p3 = (key <= qr + 3) ? __expf(acc[3]) * li[3] : 0.f;
                const int cc = (h << 4) + c16;
                pf32[wv][g * 4 + 0][cc] = p0;
                pf32[wv][g * 4 + 1][cc] = p1;
                pf32[wv][g * 4 + 2][cc] = p2;
                pf32[wv][g * 4 + 3][cc] = p3;
                pbf[wv][g * 4 + 0][cc] = f2bf(p0);
                pbf[wv][g * 4 + 1][cc] = f2bf(p1);
                pbf[wv][g * 4 + 2][cc] = f2bf(p2);
                pbf[wv][g * 4 + 3][cc] = f2bf(p3);
            }
            // vectorized attn store: lane -> row=lane>>2, cols (lane&3)*8 .. +7
            {
                const int pr  = lane >> 2;
                const int pc  = (lane & 3) * 8;
                const float4 v0 = *(const float4*)&pf32[wv][pr][pc];
                const float4 v1 = *(const float4*)&pf32[wv][pr][pc + 4];
                float* dst = outA + (qbase + pr) * SEQ + kb32 + pc;
                *(float4*)(dst)     = v0;
                *(float4*)(dst + 4) = v1;
            }
            // PV: A = P[row=c16][k=8g+j]; B = Vt[d=16dt+c16][key=kb32+8g+j]
            const bf16x8 pa = *(bf16x8*)&pbf[wv][c16][g * 8];
            #pragma unroll
            for (int dt = 0; dt < 8; ++dt) {
                const bf16x8 vf = *(const bf16x8*)(Vbh + (size_t)(dt * 16 + c16) * SEQ + kb32 + g * 8);
                oacc[dt] = __builtin_amdgcn_mfma_f32_16x16x32_bf16(pa, vf, oacc[dt], 0, 0, 0);
            }
        }

        // ---- O: cross-wave reduce in LDS (serial, 8 barriers) ----
        for (int wp = 0; wp < 8; ++wp) {
            if (wv == wp) {
                #pragma unroll
                for (int dt = 0; dt < 8; ++dt) {
                    #pragma unroll
                    for (int r = 0; r < 4; ++r) {
                        if (wp == 0) Osh[g * 4 + r][dt * 16 + c16]  = oacc[dt][r];
                        else         Osh[g * 4 + r][dt * 16 + c16] += oacc[dt][r];
                    }
                }
            }
            __syncthreads();
        }
        {
            const int r  = tid >> 5;            // 16 rows, 32 threads each
            const int d0 = (tid & 31) * 4;
            float4 o;
            o.x = Osh[r][d0 + 0]; o.y = Osh[r][d0 + 1];
            o.z = Osh[r][d0 + 2]; o.w = Osh[r][d0 + 3];
            *(float4*)(outO + (qbase + r) * DH + d0) = o;
        }

        // ---- zero-fill causal tail: rows qw..qw+15, cols nt*32 .. SEQ ----
        {
            const int r = tid >> 5;
            float* zrow = outA + (qbase + r) * SEQ;
            const float4 z = {0.f, 0.f, 0.f, 0.f};
            for (int c = nt * 32 + (tid & 31) * 4; c < SEQ; c += 128) {
                *(float4*)(zrow + c) = z;
            }
        }
    }
}

// ---------- fallback (round-4 kernel, used only if ws too small) ----------
__global__ __launch_bounds__(256) void attn_fallback(
    const float* __restrict__ qp, const float* __restrict__ kp,
    const float* __restrict__ vp, float* __restrict__ outO,
    float* __restrict__ outA)
{
    const int qt   = blockIdx.x;
    const int bh   = blockIdx.y;
    const int wv   = threadIdx.x >> 6;
    const int lane = threadIdx.x & 63;
    const int c16  = lane & 15;
    const int g    = lane >> 4;
    const int qw = qt * 64 + wv * 16;
    const size_t qbase = (size_t)bh * SEQ + qw;
    const float invT = 0.08838834764831845f;

    bf16x8 qf[4];
    {
        const float* qrow = qp + (qbase + c16) * DH + g * 8;
        #pragma unroll
        for (int c = 0; c < 4; ++c) {
            const float4 a = *(const float4*)(qrow + c * 32);
            const float4 b = *(const float4*)(qrow + c * 32 + 4);
            bf16x8 f;
            f[0] = f2bf(a.x * invT); f[1] = f2bf(a.y * invT);
            f[2] = f2bf(a.z * invT); f[3] = f2bf(a.w * invT);
            f[4] = f2bf(b.x * invT); f[5] = f2bf(b.y * invT);
            f[6] = f2bf(b.z * invT); f[7] = f2bf(b.w * invT);
            qf[c] = f;
        }
    }
    const float* kbase = kp + (size_t)bh * SEQ * DH;
    const float* vbase = vp + (size_t)bh * SEQ * DH;

    float ls0 = 0.f, ls1 = 0.f, ls2 = 0.f, ls3 = 0.f;
    const int nkt16 = (qw + 16) >> 4;
    for (int t = 0; t < nkt16; ++t) {
        const int kb = t << 4;
        const float* krow = kbase + (size_t)(kb + c16) * DH + g * 8;
        f32x4 acc = {0.f, 0.f, 0.f, 0.f};
        #pragma unroll
        for (int c = 0; c < 4; ++c) {
            const float4 a = *(const float4*)(krow + c * 32);
            const float4 b = *(const float4*)(krow + c * 32 + 4);
            bf16x8 f;
            f[0] = f2bf(a.x); f[1] = f2bf(a.y); f[2] = f2bf(a.z); f[3] = f2bf(a.w);
            f[4] = f2bf(b.x); f[5] = f2bf(b.y); f[6] = f2bf(b.z); f[7] = f2bf(b.w);
            acc = __builtin_amdgcn_mfma_f32_16x16x32_bf16(qf[c], f, acc, 0, 0, 0);
        }
        const int key = kb + c16;
        const int qr  = qw + g * 4;
        if (key <= qr + 0) ls0 += __expf(acc[0]);
        if (key <= qr + 1) ls1 += __expf(acc[1]);
        if (key <= qr + 2) ls2 += __expf(acc[2]);
        if (key <= qr + 3) ls3 += __expf(acc[3]);
    }
    #pragma unroll
    for (int m = 1; m < 16; m <<= 1) {
        ls0 += __shfl_xor(ls0, m);
        ls1 += __shfl_xor(ls1, m);
        ls2 += __shfl_xor(ls2, m);
        ls3 += __shfl_xor(ls3, m);
    }
    const float li0 = 1.f / ls0, li1 = 1.f / ls1, li2 = 1.f / ls2, li3 = 1.f / ls3;

    __shared__ __align__(16) short ptileF[4][16][32];
    f32x4 oacc[8];
    #pragma unroll
    for (int d = 0; d < 8; ++d) oacc[d] = (f32x4){0.f, 0.f, 0.f, 0.f};

    const int n32 = (qw + 47) >> 5;
    for (int t = 0; t < n32; ++t) {
        const int kb32 = t << 5;
        #pragma unroll
        for (int h = 0; h < 2; ++h) {
            const int kb = kb32 + h * 16;
            const float* krow = kbase + (size_t)(kb + c16) * DH + g * 8;
            f32x4 acc = {0.f, 0.f, 0.f, 0.f};
            #pragma unroll
            for (int c = 0; c < 4; ++c) {
                const float4 a = *(const float4*)(krow + c * 32);
                const float4 b = *(const float4*)(krow + c * 32 + 4);
                bf16x8 f;
                f[0] = f2bf(a.x); f[1] = f2bf(a.y); f[2] = f2bf(a.z); f[3] = f2bf(a.w);
                f[4] = f2bf(b.x); f[5] = f2bf(b.y); f[6] = f2bf(b.z); f[7] = f2bf(b.w);
                acc = __builtin_amdgcn_mfma_f32_16x16x32_bf16(qf[c], f, acc, 0, 0, 0);
            }
            const int key = kb + c16;
            const int qr  = qw + g * 4;
            const float p0 = (key <= qr + 0) ? __expf(acc[0]) * li0 : 0.f;
            const float p1 = (key <= qr + 1) ? __expf(acc[1]) * li1 : 0.f;
            const float p2 = (key <= qr + 2) ? __expf(acc[2]) * li2 : 0.f;
            const float p3 = (key <= qr + 3) ? __expf(acc[3]) * li3 : 0.f;
            outA[(qbase + g * 4 + 0) * SEQ + kb + c16] = p0;
            outA[(qbase + g * 4 + 1) * SEQ + kb + c16] = p1;
            outA[(qbase + g * 4 + 2) * SEQ + kb + c16] = p2;
            outA[(qbase + g * 4 + 3) * SEQ + kb + c16] = p3;
            ptileF[wv][g * 4 + 0][h * 16 + c16] = f2bf(p0);
            ptileF[wv][g * 4 + 1][h * 16 + c16] = f2bf(p1);
            ptileF[wv][g * 4 + 2][h * 16 + c16] = f2bf(p2);
            ptileF[wv][g * 4 + 3][h * 16 + c16] = f2bf(p3);
        }
        bf16x8 pa = *(bf16x8*)&ptileF[wv][c16][g * 8];
        #pragma unroll
        for (int dt = 0; dt < 8; ++dt) {
            const float* vcol = vbase + (size_t)(kb32 + g * 8) * DH + dt * 16 + c16;
            bf16x8 vf;
            #pragma unroll
            for (int i = 0; i < 8; ++i) vf[i] = f2bf(vcol[(size_t)i * DH]);
            oacc[dt] = __builtin_amdgcn_mfma_f32_16x16x32_bf16(pa, vf, oacc[dt], 0, 0, 0);
        }
    }
    {
        const float4 z4 = {0.f, 0.f, 0.f, 0.f};
        float* zrow = outA + (qbase + (lane >> 2)) * SEQ;
        for (int c = n32 * 32 + (lane & 3) * 8; c < SEQ; c += 32) {
            *(float4*)(zrow + c)     = z4;
            *(float4*)(zrow + c + 4) = z4;
        }
    }
    #pragma unroll
    for (int dt = 0; dt < 8; ++dt) {
        #pragma unroll
        for (int r = 0; r < 4; ++r) {
            outO[(qbase + g * 4 + r) * DH + dt * 16 + c16] = oacc[dt][r];
        }
    }
}

extern "C" void kernel_launch(void* const* d_in, const int* in_sizes, int n_in,
                              void* d_out, int out_size, void* d_ws, size_t ws_size,
                              hipStream_t stream) {
    (void)in_sizes; (void)n_in; (void)out_size;
    const float* q = (const float*)d_in[0];
    const float* k = (const float*)d_in[1];
    const float* v = (const float*)d_in[2];
    float* outO = (float*)d_out;                   // [BH, S, D] f32
    float* outA = outO + (size_t)BH_N * SEQ * DH;  // [BH, S, S] f32

    const size_t need = (size_t)BH_N * SEQ * DH * sizeof(unsigned short) * 2;  // Kb + Vt
    if (ws_size >= need) {
        unsigned short* Kb = (unsigned short*)d_ws;
        unsigned short* Vt = Kb + (size_t)BH_N * SEQ * DH;
        prep_kv<<<dim3(SEQ / 64, BH_N), 256, 0, stream>>>(k, v, Kb, Vt);
        attn_main<<<dim3(64, BH_N), 512, 0, stream>>>(q, Kb, Vt, outO, outA);
    } else {
        attn_fallback<<<dim3(SEQ / 64, BH_N), 256, 0, stream>>>(q, k, v, outO, outA);
    }
}

// Round 7
// 231.397 us; speedup vs baseline: 2.2224x; 2.2224x over previous
//
#include <hip/hip_runtime.h>
#include <hip/hip_bf16.h>

#define BH_N 16
#define SEQ 2048
#define DH 128

typedef __attribute__((ext_vector_type(8))) short bf16x8;
typedef __attribute__((ext_vector_type(4))) float f32x4;

__device__ __forceinline__ short f2bf(float x) {
    union { __hip_bfloat16 b; short s; } u;
    u.b = __float2bfloat16(x);
    return u.s;
}

// ---------- prep: K -> bf16 [bh][key][d]; V -> bf16 transposed [bh][d][key] ----------
__global__ __launch_bounds__(256) void prep_kv(
    const float* __restrict__ kp, const float* __restrict__ vp,
    unsigned short* __restrict__ Kb, unsigned short* __restrict__ Vt)
{
    const int tid  = threadIdx.x;
    const int kb64 = blockIdx.x * 64;
    const int bh   = blockIdx.y;
    const float* Ksrc = kp + ((size_t)bh * SEQ + kb64) * DH;
    const float* Vsrc = vp + ((size_t)bh * SEQ + kb64) * DH;
    unsigned short* Kdst = Kb + ((size_t)bh * SEQ + kb64) * DH;
    unsigned short* Vdst = Vt + (size_t)bh * DH * SEQ + kb64;

    #pragma unroll
    for (int i = 0; i < 8; ++i) {
        const int f4 = i * 256 + tid;
        const float4 kv = *(const float4*)(Ksrc + (size_t)f4 * 4);
        ushort4 o;
        o.x = (unsigned short)f2bf(kv.x); o.y = (unsigned short)f2bf(kv.y);
        o.z = (unsigned short)f2bf(kv.z); o.w = (unsigned short)f2bf(kv.w);
        *(ushort4*)(Kdst + (size_t)f4 * 4) = o;
    }
    const int key   = tid & 63;
    const int dbase = (tid >> 6) * 4;
    #pragma unroll
    for (int j = 0; j < 8; ++j) {
        const int d0 = dbase + j * 16;
        const float4 vv = *(const float4*)(Vsrc + (size_t)key * DH + d0);
        Vdst[(size_t)(d0 + 0) * SEQ + key] = (unsigned short)f2bf(vv.x);
        Vdst[(size_t)(d0 + 1) * SEQ + key] = (unsigned short)f2bf(vv.y);
        Vdst[(size_t)(d0 + 2) * SEQ + key] = (unsigned short)f2bf(vv.z);
        Vdst[(size_t)(d0 + 3) * SEQ + key] = (unsigned short)f2bf(vv.w);
    }
}

// ---------- main: 512 threads, 8 waves. Block = q-tiles {x, 127-x} (uniform cost) ----------
// __launch_bounds__(512, 4): 128-VGPR cap. (512, 8) forced a 64-VGPR cap -> spills ->
// 1.3 GB of scratch traffic (round-6 regression: FETCH 84->632 MB, WRITE 0.3->1.05 GB).
__global__ __launch_bounds__(512, 4) void attn_main(
    const float* __restrict__ qp, const unsigned short* __restrict__ Kb,
    const unsigned short* __restrict__ Vt, float* __restrict__ outO,
    float* __restrict__ outA)
{
    __shared__ float lspart[8][16];
    __shared__ __align__(16) float pf32[8][16][36];   // +4 pad (16B-aligned rows)
    __shared__ __align__(16) short pbf[8][16][32];
    __shared__ float Osh[16][132];

    // XCD swizzle: 8 consecutive resident blocks land on one XCD with the same bh pair
    const int lin = blockIdx.y * 64 + blockIdx.x;          // 0..1023
    const int sw  = (lin & 7) * 128 + (lin >> 3);          // bijective (1024 % 8 == 0)
    const int bh  = sw >> 6;
    const int x   = sw & 63;

    const int tid  = threadIdx.x;
    const int wv   = tid >> 6;        // 0..7
    const int lane = tid & 63;
    const int c16  = lane & 15;
    const int g    = lane >> 4;
    const float invT = 0.08838834764831845f;   // 1/sqrt(128)

    const unsigned short* Kbh = Kb + (size_t)bh * SEQ * DH;
    const unsigned short* Vbh = Vt + (size_t)bh * DH * SEQ;

    for (int half = 0; half < 2; ++half) {
        const int qt = half ? (127 - x) : x;
        const int qw = qt * 16;
        const size_t qbase = (size_t)bh * SEQ + qw;

        __syncthreads();   // guard lspart/Osh reuse across halves

        // ---- Q fragments: A[row=c16][k=32c+8g+j], pre-scaled ----
        bf16x8 qf[4];
        {
            const float* qrow = qp + (qbase + c16) * DH + g * 8;
            #pragma unroll
            for (int c = 0; c < 4; ++c) {
                const float4 a = *(const float4*)(qrow + c * 32);
                const float4 b = *(const float4*)(qrow + c * 32 + 4);
                bf16x8 f;
                f[0] = f2bf(a.x * invT); f[1] = f2bf(a.y * invT);
                f[2] = f2bf(a.z * invT); f[3] = f2bf(a.w * invT);
                f[4] = f2bf(b.x * invT); f[5] = f2bf(b.y * invT);
                f[6] = f2bf(b.z * invT); f[7] = f2bf(b.w * invT);
                qf[c] = f;
            }
        }

        // ---- phase 1: partial row sums, 16-key tiles strided by 8 waves ----
        float lsr[4] = {0.f, 0.f, 0.f, 0.f};
        const int n16 = qt + 1;
        for (int t = wv; t < n16; t += 8) {
            const int kb = t << 4;
            const unsigned short* kr = Kbh + (size_t)(kb + c16) * DH + g * 8;
            f32x4 acc = {0.f, 0.f, 0.f, 0.f};
            #pragma unroll
            for (int c = 0; c < 4; ++c) {
                const bf16x8 kf = *(const bf16x8*)(kr + c * 32);
                acc = __builtin_amdgcn_mfma_f32_16x16x32_bf16(qf[c], kf, acc, 0, 0, 0);
            }
            const int key = kb + c16;
            const int qr  = qw + g * 4;
            if (key <= qr + 0) lsr[0] += __expf(acc[0]);
            if (key <= qr + 1) lsr[1] += __expf(acc[1]);
            if (key <= qr + 2) lsr[2] += __expf(acc[2]);
            if (key <= qr + 3) lsr[3] += __expf(acc[3]);
        }
        #pragma unroll
        for (int r = 0; r < 4; ++r) {
            float s = lsr[r];
            #pragma unroll
            for (int m = 1; m < 16; m <<= 1) s += __shfl_xor(s, m);
            lsr[r] = s;
        }
        if (c16 == 0) {
            #pragma unroll
            for (int r = 0; r < 4; ++r) lspart[wv][g * 4 + r] = lsr[r];
        }
        __syncthreads();
        float li[4];
        #pragma unroll
        for (int r = 0; r < 4; ++r) {
            float s = 0.f;
            #pragma unroll
            for (int w = 0; w < 8; ++w) s += lspart[w][g * 4 + r];
            li[r] = 1.f / s;
        }

        // ---- phase 2: P writeout + O = P@V, 32-key tiles strided by 8 waves ----
        f32x4 oacc[8];
        #pragma unroll
        for (int d = 0; d < 8; ++d) oacc[d] = (f32x4){0.f, 0.f, 0.f, 0.f};

        const int nt = qw / 32 + 1;
        for (int t = wv; t < nt; t += 8) {
            const int kb32 = t << 5;
            #pragma unroll
            for (int h = 0; h < 2; ++h) {
                const int kb = kb32 + (h << 4);
                const unsigned short* kr = Kbh + (size_t)(kb + c16) * DH + g * 8;
                f32x4 acc = {0.f, 0.f, 0.f, 0.f};
                #pragma unroll
                for (int c = 0; c < 4; ++c) {
                    const bf16x8 kf = *(const bf16x8*)(kr + c * 32);
                    acc = __builtin_amdgcn_mfma_f32_16x16x32_bf16(qf[c], kf, acc, 0, 0, 0);
                }
                const int key = kb + c16;
                const int qr  = qw + g * 4;
                const float p0 = (key <= qr + 0) ? __expf(acc[0]) * li[0] : 0.f;
                const float p1 = (key <= qr + 1) ? __expf(acc[1]) * li[1] : 0.f;
                const float p2 = (key <= qr + 2) ? __expf(acc[2]) * li[2] : 0.f;
                const float p3 = (key <= qr + 3) ? __expf(acc[3]) * li[3] : 0.f;
                const int cc = (h << 4) + c16;
                pf32[wv][g * 4 + 0][cc] = p0;
                pf32[wv][g * 4 + 1][cc] = p1;
                pf32[wv][g * 4 + 2][cc] = p2;
                pf32[wv][g * 4 + 3][cc] = p3;
                pbf[wv][g * 4 + 0][cc] = f2bf(p0);
                pbf[wv][g * 4 + 1][cc] = f2bf(p1);
                pbf[wv][g * 4 + 2][cc] = f2bf(p2);
                pbf[wv][g * 4 + 3][cc] = f2bf(p3);
            }
            // vectorized attn store: lane -> row=lane>>2, cols (lane&3)*8 .. +7
            {
                const int pr  = lane >> 2;
                const int pc  = (lane & 3) * 8;
                const float4 v0 = *(const float4*)&pf32[wv][pr][pc];
                const float4 v1 = *(const float4*)&pf32[wv][pr][pc + 4];
                float* dst = outA + (qbase + pr) * SEQ + kb32 + pc;
                *(float4*)(dst)     = v0;
                *(float4*)(dst + 4) = v1;
            }
            // PV: A = P[row=c16][k=8g+j]; B = Vt[d=16dt+c16][key=kb32+8g+j]
            const bf16x8 pa = *(bf16x8*)&pbf[wv][c16][g * 8];
            #pragma unroll
            for (int dt = 0; dt < 8; ++dt) {
                const bf16x8 vf = *(const bf16x8*)(Vbh + (size_t)(dt * 16 + c16) * SEQ + kb32 + g * 8);
                oacc[dt] = __builtin_amdgcn_mfma_f32_16x16x32_bf16(pa, vf, oacc[dt], 0, 0, 0);
            }
        }

        // ---- O: cross-wave reduce in LDS (serial, 8 barriers) ----
        for (int wp = 0; wp < 8; ++wp) {
            if (wv == wp) {
                #pragma unroll
                for (int dt = 0; dt < 8; ++dt) {
                    #pragma unroll
                    for (int r = 0; r < 4; ++r) {
                        if (wp == 0) Osh[g * 4 + r][dt * 16 + c16]  = oacc[dt][r];
                        else         Osh[g * 4 + r][dt * 16 + c16] += oacc[dt][r];
                    }
                }
            }
            __syncthreads();
        }
        {
            const int r  = tid >> 5;            // 16 rows, 32 threads each
            const int d0 = (tid & 31) * 4;
            float4 o;
            o.x = Osh[r][d0 + 0]; o.y = Osh[r][d0 + 1];
            o.z = Osh[r][d0 + 2]; o.w = Osh[r][d0 + 3];
            *(float4*)(outO + (qbase + r) * DH + d0) = o;
        }

        // ---- zero-fill causal tail: rows qw..qw+15, cols nt*32 .. SEQ ----
        {
            const int r = tid >> 5;
            float* zrow = outA + (qbase + r) * SEQ;
            const float4 z = {0.f, 0.f, 0.f, 0.f};
            for (int c = nt * 32 + (tid & 31) * 4; c < SEQ; c += 128) {
                *(float4*)(zrow + c) = z;
            }
        }
    }
}

// ---------- fallback (round-4 kernel, used only if ws too small) ----------
__global__ __launch_bounds__(256) void attn_fallback(
    const float* __restrict__ qp, const float* __restrict__ kp,
    const float* __restrict__ vp, float* __restrict__ outO,
    float* __restrict__ outA)
{
    const int qt   = blockIdx.x;
    const int bh   = blockIdx.y;
    const int wv   = threadIdx.x >> 6;
    const int lane = threadIdx.x & 63;
    const int c16  = lane & 15;
    const int g    = lane >> 4;
    const int qw = qt * 64 + wv * 16;
    const size_t qbase = (size_t)bh * SEQ + qw;
    const float invT = 0.08838834764831845f;

    bf16x8 qf[4];
    {
        const float* qrow = qp + (qbase + c16) * DH + g * 8;
        #pragma unroll
        for (int c = 0; c < 4; ++c) {
            const float4 a = *(const float4*)(qrow + c * 32);
            const float4 b = *(const float4*)(qrow + c * 32 + 4);
            bf16x8 f;
            f[0] = f2bf(a.x * invT); f[1] = f2bf(a.y * invT);
            f[2] = f2bf(a.z * invT); f[3] = f2bf(a.w * invT);
            f[4] = f2bf(b.x * invT); f[5] = f2bf(b.y * invT);
            f[6] = f2bf(b.z * invT); f[7] = f2bf(b.w * invT);
            qf[c] = f;
        }
    }
    const float* kbase = kp + (size_t)bh * SEQ * DH;
    const float* vbase = vp + (size_t)bh * SEQ * DH;

    float ls0 = 0.f, ls1 = 0.f, ls2 = 0.f, ls3 = 0.f;
    const int nkt16 = (qw + 16) >> 4;
    for (int t = 0; t < nkt16; ++t) {
        const int kb = t << 4;
        const float* krow = kbase + (size_t)(kb + c16) * DH + g * 8;
        f32x4 acc = {0.f, 0.f, 0.f, 0.f};
        #pragma unroll
        for (int c = 0; c < 4; ++c) {
            const float4 a = *(const float4*)(krow + c * 32);
            const float4 b = *(const float4*)(krow + c * 32 + 4);
            bf16x8 f;
            f[0] = f2bf(a.x); f[1] = f2bf(a.y); f[2] = f2bf(a.z); f[3] = f2bf(a.w);
            f[4] = f2bf(b.x); f[5] = f2bf(b.y); f[6] = f2bf(b.z); f[7] = f2bf(b.w);
            acc = __builtin_amdgcn_mfma_f32_16x16x32_bf16(qf[c], f, acc, 0, 0, 0);
        }
        const int key = kb + c16;
        const int qr  = qw + g * 4;
        if (key <= qr + 0) ls0 += __expf(acc[0]);
        if (key <= qr + 1) ls1 += __expf(acc[1]);
        if (key <= qr + 2) ls2 += __expf(acc[2]);
        if (key <= qr + 3) ls3 += __expf(acc[3]);
    }
    #pragma unroll
    for (int m = 1; m < 16; m <<= 1) {
        ls0 += __shfl_xor(ls0, m);
        ls1 += __shfl_xor(ls1, m);
        ls2 += __shfl_xor(ls2, m);
        ls3 += __shfl_xor(ls3, m);
    }
    const float li0 = 1.f / ls0, li1 = 1.f / ls1, li2 = 1.f / ls2, li3 = 1.f / ls3;

    __shared__ __align__(16) short ptileF[4][16][32];
    f32x4 oacc[8];
    #pragma unroll
    for (int d = 0; d < 8; ++d) oacc[d] = (f32x4){0.f, 0.f, 0.f, 0.f};

    const int n32 = (qw + 47) >> 5;
    for (int t = 0; t < n32; ++t) {
        const int kb32 = t << 5;
        #pragma unroll
        for (int h = 0; h < 2; ++h) {
            const int kb = kb32 + h * 16;
            const float* krow = kbase + (size_t)(kb + c16) * DH + g * 8;
            f32x4 acc = {0.f, 0.f, 0.f, 0.f};
            #pragma unroll
            for (int c = 0; c < 4; ++c) {
                const float4 a = *(const float4*)(krow + c * 32);
                const float4 b = *(const float4*)(krow + c * 32 + 4);
                bf16x8 f;
                f[0] = f2bf(a.x); f[1] = f2bf(a.y); f[2] = f2bf(a.z); f[3] = f2bf(a.w);
                f[4] = f2bf(b.x); f[5] = f2bf(b.y); f[6] = f2bf(b.z); f[7] = f2bf(b.w);
                acc = __builtin_amdgcn_mfma_f32_16x16x32_bf16(qf[c], f, acc, 0, 0, 0);
            }
            const int key = kb + c16;
            const int qr  = qw + g * 4;
            const float p0 = (key <= qr + 0) ? __expf(acc[0]) * li0 : 0.f;
            const float p1 = (key <= qr + 1) ? __expf(acc[1]) * li1 : 0.f;
            const float p2 = (key <= qr + 2) ? __expf(acc[2]) * li2 : 0.f;
            const float p3 = (key <= qr + 3) ? __expf(acc[3]) * li3 : 0.f;
            outA[(qbase + g * 4 + 0) * SEQ + kb + c16] = p0;
            outA[(qbase + g * 4 + 1) * SEQ + kb + c16] = p1;
            outA[(qbase + g * 4 + 2) * SEQ + kb + c16] = p2;
            outA[(qbase + g * 4 + 3) * SEQ + kb + c16] = p3;
            ptileF[wv][g * 4 + 0][h * 16 + c16] = f2bf(p0);
            ptileF[wv][g * 4 + 1][h * 16 + c16] = f2bf(p1);
            ptileF[wv][g * 4 + 2][h * 16 + c16] = f2bf(p2);
            ptileF[wv][g * 4 + 3][h * 16 + c16] = f2bf(p3);
        }
        bf16x8 pa = *(bf16x8*)&ptileF[wv][c16][g * 8];
        #pragma unroll
        for (int dt = 0; dt < 8; ++dt) {
            const float* vcol = vbase + (size_t)(kb32 + g * 8) * DH + dt * 16 + c16;
            bf16x8 vf;
            #pragma unroll
            for (int i = 0; i < 8; ++i) vf[i] = f2bf(vcol[(size_t)i * DH]);
            oacc[dt] = __builtin_amdgcn_mfma_f32_16x16x32_bf16(pa, vf, oacc[dt], 0, 0, 0);
        }
    }
    {
        const float4 z4 = {0.f, 0.f, 0.f, 0.f};
        float* zrow = outA + (qbase + (lane >> 2)) * SEQ;
        for (int c = n32 * 32 + (lane & 3) * 8; c < SEQ; c += 32) {
            *(float4*)(zrow + c)     = z4;
            *(float4*)(zrow + c + 4) = z4;
        }
    }
    #pragma unroll
    for (int dt = 0; dt < 8; ++dt) {
        #pragma unroll
        for (int r = 0; r < 4; ++r) {
            outO[(qbase + g * 4 + r) * DH + dt * 16 + c16] = oacc[dt][r];
        }
    }
}

extern "C" void kernel_launch(void* const* d_in, const int* in_sizes, int n_in,
                              void* d_out, int out_size, void* d_ws, size_t ws_size,
                              hipStream_t stream) {
    (void)in_sizes; (void)n_in; (void)out_size;
    const float* q = (const float*)d_in[0];
    const float* k = (const float*)d_in[1];
    const float* v = (const float*)d_in[2];
    float* outO = (float*)d_out;                   // [BH, S, D] f32
    float* outA = outO + (size_t)BH_N * SEQ * DH;  // [BH, S, S] f32

    const size_t need = (size_t)BH_N * SEQ * DH * sizeof(unsigned short) * 2;  // Kb + Vt
    if (ws_size >= need) {
        unsigned short* Kb = (unsigned short*)d_ws;
        unsigned short* Vt = Kb + (size_t)BH_N * SEQ * DH;
        prep_kv<<<dim3(SEQ / 64, BH_N), 256, 0, stream>>>(k, v, Kb, Vt);
        attn_main<<<dim3(64, BH_N), 512, 0, stream>>>(q, Kb, Vt, outO, outA);
    } else {
        attn_fallback<<<dim3(SEQ / 64, BH_N), 256, 0, stream>>>(q, k, v, outO, outA);
    }
}